// Round 1
// baseline (282.778 us; speedup 1.0000x reference)
//
#include <hip/hip_runtime.h>
#include <hip/hip_bf16.h>
#include <math.h>

#define NN 4096
#define HH 256
#define G3 768
#define NHEADS 3
#define MAXE 128
#define ALPHA 0.2f

// ---------------- adjacency scan: node ----------------
// Per row i: find nonzeros (skip diag), accumulate Pp[i]=sum_{+} h[j], Pm[i]=sum_{-} h[j],
// node_support = Pp-Pm, dn[i] = adj[i][i].
__global__ __launch_bounds__(256) void node_scan(const float* __restrict__ adj,
                                                 const float* __restrict__ h,
                                                 float* __restrict__ Pp, float* __restrict__ Pm,
                                                 float* __restrict__ nsup, float* __restrict__ dn) {
    int i = blockIdx.x;
    int t = threadIdx.x;
    __shared__ int cnt;
    __shared__ int cols[256];
    if (t == 0) cnt = 0;
    __syncthreads();
    const float* row = adj + (size_t)i * NN;
    for (int base = t * 4; base < NN; base += 1024) {
        float4 v = *(const float4*)(row + base);
        float vv[4] = {v.x, v.y, v.z, v.w};
#pragma unroll
        for (int e = 0; e < 4; e++) {
            int j = base + e;
            float a = vv[e];
            if (j == i) {
                dn[i] = a;
            } else if (a != 0.0f) {
                int s = atomicAdd(&cnt, 1);
                if (s < 256) cols[s] = (a > 0.0f) ? (j + 1) : -(j + 1);
            }
        }
    }
    __syncthreads();
    int n = cnt < 256 ? cnt : 256;
    float accp = 0.f, accm = 0.f;
    for (int k = 0; k < n; k++) {
        int c = cols[k];
        int j = (c > 0 ? c : -c) - 1;
        float hv = h[(size_t)j * HH + t];
        if (c > 0) accp += hv; else accm += hv;
    }
    size_t o = (size_t)i * HH + t;
    Pp[o] = accp;
    Pm[o] = accm;
    nsup[o] = accp - accm;
}

// ---------------- adjacency scan: edge -> CSR ----------------
__global__ __launch_bounds__(256) void edge_scan(const float* __restrict__ adj,
                                                 int* __restrict__ csr_cols, int* __restrict__ csr_nnz,
                                                 float* __restrict__ de) {
    int i = blockIdx.x;
    int t = threadIdx.x;
    __shared__ int cnt;
    __shared__ int cols[256];
    if (t == 0) cnt = 0;
    __syncthreads();
    const float* row = adj + (size_t)i * NN;
    for (int base = t * 4; base < NN; base += 1024) {
        float4 v = *(const float4*)(row + base);
        float vv[4] = {v.x, v.y, v.z, v.w};
#pragma unroll
        for (int e = 0; e < 4; e++) {
            int j = base + e;
            float a = vv[e];
            if (j == i) {
                de[i] = a;
            } else if (a != 0.0f) {
                int s = atomicAdd(&cnt, 1);
                if (s < 256) cols[s] = (a > 0.0f) ? (j + 1) : -(j + 1);
            }
        }
    }
    __syncthreads();
    int n = cnt < MAXE ? cnt : MAXE;
    if (t == 0) csr_nnz[i] = n;
    for (int k = t; k < n; k += 256) csr_cols[(size_t)i * MAXE + k] = cols[k];
}

// ---------------- f32 GEMM: C[M,N] = A[M,K] @ B[K,N], row-major ----------------
#define BM 64
#define BN 64
#define BK 32
__global__ __launch_bounds__(256) void gemm_f32(const float* __restrict__ A, const float* __restrict__ B,
                                                float* __restrict__ C, int M, int N, int K) {
    __shared__ float a_s[BK][BM];
    __shared__ float b_s[BK][BN];
    int tid = threadIdx.x;
    int tx = tid % 16, ty = tid / 16;
    int i0 = blockIdx.x * BM;
    int c0 = blockIdx.y * BN;
    float acc[4][4] = {};
    for (int k0 = 0; k0 < K; k0 += BK) {
#pragma unroll
        for (int it = 0; it < 2; it++) {
            int idx = tid + it * 256;
            int r = idx / 8;
            int kq = (idx % 8) * 4;
            float4 v = *(const float4*)(A + (size_t)(i0 + r) * K + k0 + kq);
            a_s[kq + 0][r] = v.x; a_s[kq + 1][r] = v.y; a_s[kq + 2][r] = v.z; a_s[kq + 3][r] = v.w;
        }
#pragma unroll
        for (int it = 0; it < 2; it++) {
            int idx = tid + it * 256;
            int kk = idx / 16;
            int cq = (idx % 16) * 4;
            *(float4*)(&b_s[kk][cq]) = *(const float4*)(B + (size_t)(k0 + kk) * N + c0 + cq);
        }
        __syncthreads();
#pragma unroll
        for (int kk = 0; kk < BK; kk++) {
            float4 av = *(const float4*)(&a_s[kk][ty * 4]);
            float4 bv = *(const float4*)(&b_s[kk][tx * 4]);
            float aa[4] = {av.x, av.y, av.z, av.w};
            float bb[4] = {bv.x, bv.y, bv.z, bv.w};
#pragma unroll
            for (int r = 0; r < 4; r++)
#pragma unroll
                for (int c = 0; c < 4; c++) acc[r][c] += aa[r] * bb[c];
        }
        __syncthreads();
    }
#pragma unroll
    for (int r = 0; r < 4; r++) {
        float4 v = {acc[r][0], acc[r][1], acc[r][2], acc[r][3]};
        *(float4*)(C + (size_t)(i0 + ty * 4 + r) * N + c0 + tx * 4) = v;
    }
}

// ---------------- weight transpose: out[c][r] = in[r][c] ----------------
__global__ __launch_bounds__(256) void transpose_k(const float* __restrict__ in, float* __restrict__ out,
                                                   int R, int Cc) {
    __shared__ float tile[32][33];
    int bx = blockIdx.x * 32, by = blockIdx.y * 32;
    int tx = threadIdx.x % 32, ty = threadIdx.x / 32;
    for (int rr = ty; rr < 32; rr += 8) {
        int r = by + rr, c = bx + tx;
        tile[rr][tx] = (r < R && c < Cc) ? in[(size_t)r * Cc + c] : 0.f;
    }
    __syncthreads();
    for (int rr = ty; rr < 32; rr += 8) {
        int c = bx + rr, r = by + tx;
        if (c < Cc && r < R) out[(size_t)c * R + r] = tile[tx][rr];
    }
}

// ---------------- c0 = W@a_top, c1 = W@a_bot per head ----------------
__global__ __launch_bounds__(256) void gat_c(const float* __restrict__ W, const float* __restrict__ a,
                                             float* __restrict__ c0, float* __restrict__ c1) {
    int hd = blockIdx.x;
    int t = threadIdx.x;
    __shared__ float a_s[512];
    a_s[t] = a[(size_t)hd * 512 + t];
    a_s[t + 256] = a[(size_t)hd * 512 + 256 + t];
    __syncthreads();
    const float* Wr = W + (size_t)hd * HH * HH + (size_t)t * HH;
    float s0 = 0.f, s1 = 0.f;
    for (int c = 0; c < HH; c++) {
        float w = Wr[c];
        s0 += w * a_s[c];
        s1 += w * a_s[256 + c];
    }
    c0[hd * HH + t] = s0;
    c1[hd * HH + t] = s1;
}

__device__ inline float lrelu(float x) { return x > 0.f ? x : ALPHA * x; }

// ---------------- e_plus/e_minus = LReLU(Pp.c0 + Pm.c1), LReLU(Pm.c0 + Pp.c1) ----------------
__global__ __launch_bounds__(256) void gat_e(const float* __restrict__ Pp, const float* __restrict__ Pm,
                                             const float* __restrict__ c0, const float* __restrict__ c1,
                                             float* __restrict__ ep, float* __restrict__ em) {
    int i = blockIdx.x;
    int t = threadIdx.x;
    __shared__ float red[256];
    float pp = Pp[(size_t)i * HH + t];
    float pm = Pm[(size_t)i * HH + t];
    for (int hd = 0; hd < NHEADS; hd++) {
        float v0 = c0[hd * HH + t], v1 = c1[hd * HH + t];
        red[t] = pp * v0 + pm * v1;
        __syncthreads();
        for (int s = 128; s > 0; s >>= 1) {
            if (t < s) red[t] += red[t + s];
            __syncthreads();
        }
        if (t == 0) ep[(size_t)hd * NN + i] = lrelu(red[0]);
        __syncthreads();
        red[t] = pm * v0 + pp * v1;
        __syncthreads();
        for (int s = 128; s > 0; s >>= 1) {
            if (t < s) red[t] += red[t + s];
            __syncthreads();
        }
        if (t == 0) em[(size_t)hd * NN + i] = lrelu(red[0]);
        __syncthreads();
    }
}

// ---------------- GAT sparse output: edge_support = mean_heads (att*sign) @ hW ----------------
__global__ __launch_bounds__(256) void gat_out(const int* __restrict__ csr_cols, const int* __restrict__ csr_nnz,
                                               const float* __restrict__ ep, const float* __restrict__ em,
                                               const float* __restrict__ hW, float* __restrict__ esup) {
    int i = blockIdx.x;
    int t = threadIdx.x;
    __shared__ int cols_s[MAXE];
    __shared__ float v_s[MAXE];
    int n = csr_nnz[i];
    for (int k = t; k < n; k += 256) cols_s[k] = csr_cols[(size_t)i * MAXE + k];
    __syncthreads();
    float acc = 0.f;
    for (int hd = 0; hd < NHEADS; hd++) {
        if (t < n) {
            int c = cols_s[t];
            int j = (c > 0 ? c : -c) - 1;
            v_s[t] = (c > 0) ? ep[(size_t)hd * NN + j] : em[(size_t)hd * NN + j];
        }
        __syncthreads();
        if (n > 0) {
            float m = -1e30f;
            for (int k = 0; k < n; k++) m = fmaxf(m, v_s[k]);
            float s = 0.f;
            float part = 0.f;
            const float* hWh = hW + (size_t)hd * NN * HH;
            for (int k = 0; k < n; k++) {
                float w = __expf(v_s[k] - m);
                s += w;
                int c = cols_s[k];
                int j = (c > 0 ? c : -c) - 1;
                part += (c > 0 ? w : -w) * hWh[(size_t)j * HH + t];
            }
            acc += part / s;
        }
        __syncthreads();
    }
    esup[(size_t)i * HH + t] = acc * (1.f / 3.f);
}

// ---------------- GRU gates ----------------
__global__ __launch_bounds__(256) void gru_gate(const float* __restrict__ gi, const float* __restrict__ gh,
                                                const float* __restrict__ bih, const float* __restrict__ bhh,
                                                const float* __restrict__ hstate, float* __restrict__ out) {
    int i = blockIdx.x;
    int t = threadIdx.x;
    size_t gbase = (size_t)i * G3;
    float ir = gi[gbase + t] + bih[t];
    float iz = gi[gbase + 256 + t] + bih[256 + t];
    float in_ = gi[gbase + 512 + t] + bih[512 + t];
    float hr = gh[gbase + t] + bhh[t];
    float hz = gh[gbase + 256 + t] + bhh[256 + t];
    float hn = gh[gbase + 512 + t] + bhh[512 + t];
    float r = 1.f / (1.f + expf(-(ir + hr)));
    float z = 1.f / (1.f + expf(-(iz + hz)));
    float nv = tanhf(in_ + r * hn);
    size_t o = (size_t)i * HH + t;
    out[o] = (1.f - z) * nv + z * hstate[o];
}

// ---------------- combine ----------------
__global__ __launch_bounds__(256) void combine_k(const float* __restrict__ de, const float* __restrict__ dn,
                                                 const float* __restrict__ eout, const float* __restrict__ nout,
                                                 float* __restrict__ out) {
    int i = blockIdx.x;
    int t = threadIdx.x;
    size_t o = (size_t)i * HH + t;
    out[o] = de[i] * eout[o] + dn[i] * nout[o];
}

extern "C" void kernel_launch(void* const* d_in, const int* in_sizes, int n_in,
                              void* d_out, int out_size, void* d_ws, size_t ws_size,
                              hipStream_t stream) {
    const float* h        = (const float*)d_in[0];
    const float* node_adj = (const float*)d_in[1];
    const float* edge_adj = (const float*)d_in[2];
    const float* gat_W    = (const float*)d_in[3];
    const float* gat_a    = (const float*)d_in[4];
    const float* e_Wih    = (const float*)d_in[5];
    const float* e_Whh    = (const float*)d_in[6];
    const float* e_bih    = (const float*)d_in[7];
    const float* e_bhh    = (const float*)d_in[8];
    const float* n_Wih    = (const float*)d_in[9];
    const float* n_Whh    = (const float*)d_in[10];
    const float* n_bih    = (const float*)d_in[11];
    const float* n_bhh    = (const float*)d_in[12];
    float* out = (float*)d_out;

    float* ws = (float*)d_ws;
    size_t off = 0;
    float* Pp   = ws + off; off += (size_t)NN * HH;
    float* Pm   = ws + off; off += (size_t)NN * HH;
    float* nsup = ws + off; off += (size_t)NN * HH;
    float* hW   = ws + off; off += (size_t)NHEADS * NN * HH;
    float* esup = ws + off; off += (size_t)NN * HH;
    float* gi   = ws + off; off += (size_t)NN * G3;
    float* gh   = ws + off; off += (size_t)NN * G3;
    float* eout = ws + off; off += (size_t)NN * HH;
    float* nout = ws + off; off += (size_t)NN * HH;
    float* ep   = ws + off; off += (size_t)NHEADS * NN;
    float* em   = ws + off; off += (size_t)NHEADS * NN;
    float* c0   = ws + off; off += (size_t)NHEADS * HH;
    float* c1   = ws + off; off += (size_t)NHEADS * HH;
    float* dn   = ws + off; off += NN;
    float* de   = ws + off; off += NN;
    float* WTei = ws + off; off += (size_t)HH * G3;  // edge_Wih^T [256,768]
    float* WTeh = ws + off; off += (size_t)HH * G3;
    float* WTni = ws + off; off += (size_t)HH * G3;
    float* WTnh = ws + off; off += (size_t)HH * G3;
    int* csr_cols = (int*)(ws + off); off += (size_t)NN * MAXE;
    int* csr_nnz  = (int*)(ws + off); off += NN;

    dim3 b256(256);

    // 1. weight transposes [768,256] -> [256,768]
    {
        dim3 g(HH / 32, G3 / 32);
        transpose_k<<<g, b256, 0, stream>>>(e_Wih, WTei, G3, HH);
        transpose_k<<<g, b256, 0, stream>>>(e_Whh, WTeh, G3, HH);
        transpose_k<<<g, b256, 0, stream>>>(n_Wih, WTni, G3, HH);
        transpose_k<<<g, b256, 0, stream>>>(n_Whh, WTnh, G3, HH);
    }

    // 2-3. adjacency scans
    node_scan<<<NN, b256, 0, stream>>>(node_adj, h, Pp, Pm, nsup, dn);
    edge_scan<<<NN, b256, 0, stream>>>(edge_adj, csr_cols, csr_nnz, de);

    // 4. hW = h @ W per head
    for (int hd = 0; hd < NHEADS; hd++) {
        dim3 g(NN / BM, HH / BN);
        gemm_f32<<<g, b256, 0, stream>>>(h, gat_W + (size_t)hd * HH * HH,
                                         hW + (size_t)hd * NN * HH, NN, HH, HH);
    }

    // 5. c0/c1 per head
    gat_c<<<NHEADS, b256, 0, stream>>>(gat_W, gat_a, c0, c1);

    // 6. e_plus/e_minus
    gat_e<<<NN, b256, 0, stream>>>(Pp, Pm, c0, c1, ep, em);

    // 7. GAT sparse attention output -> edge_support
    gat_out<<<NN, b256, 0, stream>>>(csr_cols, csr_nnz, ep, em, hW, esup);

    // 8. edge GRU: gi = nsup @ WihT, gh = h @ WhhT
    {
        dim3 g(NN / BM, G3 / BN);
        gemm_f32<<<g, b256, 0, stream>>>(nsup, WTei, gi, NN, G3, HH);
        gemm_f32<<<g, b256, 0, stream>>>(h, WTeh, gh, NN, G3, HH);
    }
    gru_gate<<<NN, b256, 0, stream>>>(gi, gh, e_bih, e_bhh, h, eout);

    // 10. node GRU
    {
        dim3 g(NN / BM, G3 / BN);
        gemm_f32<<<g, b256, 0, stream>>>(esup, WTni, gi, NN, G3, HH);
        gemm_f32<<<g, b256, 0, stream>>>(h, WTnh, gh, NN, G3, HH);
    }
    gru_gate<<<NN, b256, 0, stream>>>(gi, gh, n_bih, n_bhh, h, nout);

    // 12. out = de*edge_out + dn*node_out
    combine_k<<<NN, b256, 0, stream>>>(de, dn, eout, nout, out);
}

// Round 2
// 130.539 us; speedup vs baseline: 2.1662x; 2.1662x over previous
//
#include <hip/hip_runtime.h>
#include <hip/hip_bf16.h>
#include <math.h>

#define NN 4096
#define HH 256
#define G3 768
#define NHEADS 3
#define MAXE 128
#define ALPHA 0.2f

typedef __bf16 bf16;
typedef __attribute__((ext_vector_type(8))) __bf16 bf16x8;
typedef __attribute__((ext_vector_type(4))) float f32x4;

__device__ __forceinline__ void async_copy16(void* lds, const void* g) {
    __builtin_amdgcn_global_load_lds((const __attribute__((address_space(1))) void*)g,
                                     (__attribute__((address_space(3))) void*)lds, 16, 0, 0);
}

__device__ inline float lrelu(float x) { return x > 0.f ? x : ALPHA * x; }

// ---------------- f32 -> bf16 convert (vectorized) ----------------
__global__ __launch_bounds__(256) void convert_bf16(const float* __restrict__ in,
                                                    bf16* __restrict__ out, int n4) {
    int idx = blockIdx.x * 256 + threadIdx.x;
    if (idx < n4) {
        float4 v = *(const float4*)(in + (size_t)idx * 4);
        union { bf16 b[4]; ushort4 u; } o;
        o.b[0] = (bf16)v.x; o.b[1] = (bf16)v.y; o.b[2] = (bf16)v.z; o.b[3] = (bf16)v.w;
        *(ushort4*)(out + (size_t)idx * 4) = o.u;
    }
}

// 4 weight matrices [768,256] f32 -> bf16, selected by blockIdx.y
__global__ __launch_bounds__(256) void convert4_bf16(const float* __restrict__ w0, const float* __restrict__ w1,
                                                     const float* __restrict__ w2, const float* __restrict__ w3,
                                                     bf16* __restrict__ o0, bf16* __restrict__ o1,
                                                     bf16* __restrict__ o2, bf16* __restrict__ o3) {
    const float* in = blockIdx.y == 0 ? w0 : (blockIdx.y == 1 ? w1 : (blockIdx.y == 2 ? w2 : w3));
    bf16* out = blockIdx.y == 0 ? o0 : (blockIdx.y == 1 ? o1 : (blockIdx.y == 2 ? o2 : o3));
    int idx = blockIdx.x * 256 + threadIdx.x;  // n4 = 768*256/4 = 49152
    float4 v = *(const float4*)(in + (size_t)idx * 4);
    union { bf16 b[4]; ushort4 u; } o;
    o.b[0] = (bf16)v.x; o.b[1] = (bf16)v.y; o.b[2] = (bf16)v.z; o.b[3] = (bf16)v.w;
    *(ushort4*)(out + (size_t)idx * 4) = o.u;
}

// gat_W [3][256][256] -> transposed bf16: Wt[hd][n][k] = W[hd][k][n]
__global__ __launch_bounds__(256) void transW_bf16(const float* __restrict__ W, bf16* __restrict__ Wt) {
    __shared__ float tile[32][33];
    int hd = blockIdx.z;
    int k0 = blockIdx.x * 32, n0 = blockIdx.y * 32;
    int tx = threadIdx.x % 32, ty = threadIdx.x / 32;
    const float* Wh = W + (size_t)hd * HH * HH;
    for (int r = ty; r < 32; r += 8) tile[r][tx] = Wh[(size_t)(k0 + r) * HH + n0 + tx];
    __syncthreads();
    bf16* Wth = Wt + (size_t)hd * HH * HH;
    for (int r = ty; r < 32; r += 8) Wth[(size_t)(n0 + r) * HH + k0 + tx] = (bf16)tile[tx][r];
}

// ---------------- adjacency scan: node ----------------
__global__ __launch_bounds__(256) void node_scan(const float* __restrict__ adj,
                                                 const float* __restrict__ h,
                                                 float* __restrict__ Pp, float* __restrict__ Pm,
                                                 bf16* __restrict__ nsupb, float* __restrict__ dn) {
    int i = blockIdx.x;
    int t = threadIdx.x;
    __shared__ int cnt;
    __shared__ int cols[256];
    if (t == 0) cnt = 0;
    __syncthreads();
    const float* row = adj + (size_t)i * NN;
    for (int base = t * 4; base < NN; base += 1024) {
        float4 v = *(const float4*)(row + base);
        float vv[4] = {v.x, v.y, v.z, v.w};
#pragma unroll
        for (int e = 0; e < 4; e++) {
            int j = base + e;
            float a = vv[e];
            if (j == i) {
                dn[i] = a;
            } else if (a != 0.0f) {
                int s = atomicAdd(&cnt, 1);
                if (s < 256) cols[s] = (a > 0.0f) ? (j + 1) : -(j + 1);
            }
        }
    }
    __syncthreads();
    int n = cnt < 256 ? cnt : 256;
    float accp = 0.f, accm = 0.f;
    for (int k = 0; k < n; k++) {
        int c = cols[k];
        int j = (c > 0 ? c : -c) - 1;
        float hv = h[(size_t)j * HH + t];
        if (c > 0) accp += hv; else accm += hv;
    }
    size_t o = (size_t)i * HH + t;
    Pp[o] = accp;
    Pm[o] = accm;
    nsupb[o] = (bf16)(accp - accm);
}

// ---------------- adjacency scan: edge -> CSR ----------------
__global__ __launch_bounds__(256) void edge_scan(const float* __restrict__ adj,
                                                 int* __restrict__ csr_cols, int* __restrict__ csr_nnz,
                                                 float* __restrict__ de) {
    int i = blockIdx.x;
    int t = threadIdx.x;
    __shared__ int cnt;
    __shared__ int cols[256];
    if (t == 0) cnt = 0;
    __syncthreads();
    const float* row = adj + (size_t)i * NN;
    for (int base = t * 4; base < NN; base += 1024) {
        float4 v = *(const float4*)(row + base);
        float vv[4] = {v.x, v.y, v.z, v.w};
#pragma unroll
        for (int e = 0; e < 4; e++) {
            int j = base + e;
            float a = vv[e];
            if (j == i) {
                de[i] = a;
            } else if (a != 0.0f) {
                int s = atomicAdd(&cnt, 1);
                if (s < 256) cols[s] = (a > 0.0f) ? (j + 1) : -(j + 1);
            }
        }
    }
    __syncthreads();
    int n = cnt < MAXE ? cnt : MAXE;
    if (t == 0) csr_nnz[i] = n;
    for (int k = t; k < n; k += 256) csr_cols[(size_t)i * MAXE + k] = cols[k];
}

// ---------------- bf16 MFMA GEMM: C[M,N](bf16) = A[M,256] @ Bt[N,256]^T ----------------
// m97 structure: 128x128 tile, 4 waves (2x2 of 64x64), BK=32, global_load_lds width 16.
// blockIdx.z selects (A,B,C) pointer triple for batching.
__global__ __launch_bounds__(256) void gemm_bt(const bf16* __restrict__ A0, const bf16* __restrict__ A1, const bf16* __restrict__ A2,
                                               const bf16* __restrict__ B0, const bf16* __restrict__ B1, const bf16* __restrict__ B2,
                                               bf16* __restrict__ C0, bf16* __restrict__ C1, bf16* __restrict__ C2,
                                               int N) {
    __shared__ bf16 a_s[128 * 32];
    __shared__ bf16 b_s[128 * 32];
    int z = blockIdx.z;
    const bf16* A = z == 0 ? A0 : (z == 1 ? A1 : A2);
    const bf16* Bt = z == 0 ? B0 : (z == 1 ? B1 : B2);
    bf16* C = z == 0 ? C0 : (z == 1 ? C1 : C2);

    int tid = threadIdx.x;
    int lane = tid & 63, wid = tid >> 6;
    int wr = (wid >> 1) * 64, wc = (wid & 1) * 64;
    int i0 = blockIdx.x * 128;
    int c0n = blockIdx.y * 128;

    f32x4 acc[4][4] = {};
    int kq = (lane >> 4) * 8;

    for (int k0 = 0; k0 < 256; k0 += 32) {
        __syncthreads();
#pragma unroll
        for (int it = 0; it < 2; it++) {
            int ch = it * 256 + tid;
            int r = ch >> 2, c16 = ch & 3;
            async_copy16(&a_s[ch * 8], A + (size_t)(i0 + r) * 256 + k0 + c16 * 8);
            async_copy16(&b_s[ch * 8], Bt + (size_t)(c0n + r) * 256 + k0 + c16 * 8);
        }
        __syncthreads();
        bf16x8 af[4], bf[4];
#pragma unroll
        for (int m = 0; m < 4; m++) af[m] = *(const bf16x8*)&a_s[(wr + m * 16 + (lane & 15)) * 32 + kq];
#pragma unroll
        for (int n = 0; n < 4; n++) bf[n] = *(const bf16x8*)&b_s[(wc + n * 16 + (lane & 15)) * 32 + kq];
#pragma unroll
        for (int m = 0; m < 4; m++)
#pragma unroll
            for (int n = 0; n < 4; n++)
                acc[m][n] = __builtin_amdgcn_mfma_f32_16x16x32_bf16(af[m], bf[n], acc[m][n], 0, 0, 0);
    }
    // C/D layout: col = lane&15, row = (lane>>4)*4 + j   [m89/m91 verified]
#pragma unroll
    for (int m = 0; m < 4; m++) {
#pragma unroll
        for (int n = 0; n < 4; n++) {
            int row = i0 + wr + m * 16 + (lane >> 4) * 4;
            int col = c0n + wc + n * 16 + (lane & 15);
#pragma unroll
            for (int j = 0; j < 4; j++)
                C[(size_t)(row + j) * N + col] = (bf16)acc[m][n][j];
        }
    }
}

// ---------------- c0 = W@a_top, c1 = W@a_bot per head (f32) ----------------
__global__ __launch_bounds__(256) void gat_c(const float* __restrict__ W, const float* __restrict__ a,
                                             float* __restrict__ c0, float* __restrict__ c1) {
    int hd = blockIdx.x;
    int t = threadIdx.x;
    __shared__ float a_s[512];
    a_s[t] = a[(size_t)hd * 512 + t];
    a_s[t + 256] = a[(size_t)hd * 512 + 256 + t];
    __syncthreads();
    const float* Wr = W + (size_t)hd * HH * HH + (size_t)t * HH;
    float s0 = 0.f, s1 = 0.f;
    for (int c = 0; c < HH; c++) {
        float w = Wr[c];
        s0 += w * a_s[c];
        s1 += w * a_s[256 + c];
    }
    c0[hd * HH + t] = s0;
    c1[hd * HH + t] = s1;
}

// ---------------- e_plus/e_minus: one wave per row, shuffle reduce ----------------
__global__ __launch_bounds__(256) void gat_e(const float* __restrict__ Pp, const float* __restrict__ Pm,
                                             const float* __restrict__ c0, const float* __restrict__ c1,
                                             float* __restrict__ ep, float* __restrict__ em) {
    __shared__ float c0s[NHEADS * HH], c1s[NHEADS * HH];
    int t = threadIdx.x;
    for (int x = t; x < NHEADS * HH; x += 256) { c0s[x] = c0[x]; c1s[x] = c1[x]; }
    __syncthreads();
    int wid = t >> 6, lane = t & 63;
    int i = blockIdx.x * 4 + wid;
    float4 p = *(const float4*)(Pp + (size_t)i * HH + lane * 4);
    float4 m = *(const float4*)(Pm + (size_t)i * HH + lane * 4);
#pragma unroll
    for (int hd = 0; hd < NHEADS; hd++) {
        float4 a = *(const float4*)(c0s + hd * HH + lane * 4);
        float4 b = *(const float4*)(c1s + hd * HH + lane * 4);
        float s0 = p.x * a.x + p.y * a.y + p.z * a.z + p.w * a.w
                 + m.x * b.x + m.y * b.y + m.z * b.z + m.w * b.w;
        float s1 = m.x * a.x + m.y * a.y + m.z * a.z + m.w * a.w
                 + p.x * b.x + p.y * b.y + p.z * b.z + p.w * b.w;
#pragma unroll
        for (int off = 32; off; off >>= 1) {
            s0 += __shfl_down(s0, off);
            s1 += __shfl_down(s1, off);
        }
        if (lane == 0) {
            ep[(size_t)hd * NN + i] = lrelu(s0);
            em[(size_t)hd * NN + i] = lrelu(s1);
        }
    }
}

// ---------------- GAT sparse output ----------------
// Phase 1: 3 waves compute the 3 heads' normalized signed softmax weights (shuffle reduce).
// Phase 2: all 256 threads do the weighted bf16 gather.
__global__ __launch_bounds__(256) void gat_out(const int* __restrict__ csr_cols, const int* __restrict__ csr_nnz,
                                               const float* __restrict__ ep, const float* __restrict__ em,
                                               const bf16* __restrict__ hWb, bf16* __restrict__ esupb) {
    int i = blockIdx.x, t = threadIdx.x;
    __shared__ int cols_s[MAXE];
    __shared__ int js[MAXE];
    __shared__ float w_s[NHEADS][MAXE];
    int n = csr_nnz[i];
    if (t < MAXE && t < n) {
        int c = csr_cols[(size_t)i * MAXE + t];
        cols_s[t] = c;
        js[t] = (c > 0 ? c : -c) - 1;
    }
    __syncthreads();
    int wid = t >> 6, lane = t & 63;
    if (wid < NHEADS) {
        int hd = wid;
        const float* eph = ep + (size_t)hd * NN;
        const float* emh = em + (size_t)hd * NN;
        float v0 = -1e30f, v1 = -1e30f;
        if (lane < n)      { int c = cols_s[lane];      v0 = c > 0 ? eph[js[lane]]      : emh[js[lane]]; }
        if (lane + 64 < n) { int c = cols_s[lane + 64]; v1 = c > 0 ? eph[js[lane + 64]] : emh[js[lane + 64]]; }
        float mx = fmaxf(v0, v1);
#pragma unroll
        for (int off = 32; off; off >>= 1) mx = fmaxf(mx, __shfl_xor(mx, off));
        float w0 = (lane < n) ? __expf(v0 - mx) : 0.f;
        float w1 = (lane + 64 < n) ? __expf(v1 - mx) : 0.f;
        float s = w0 + w1;
#pragma unroll
        for (int off = 32; off; off >>= 1) s += __shfl_xor(s, off);
        float inv = 1.f / s;
        if (lane < n)      w_s[hd][lane]      = (cols_s[lane] > 0 ? w0 : -w0) * inv;
        if (lane + 64 < n) w_s[hd][lane + 64] = (cols_s[lane + 64] > 0 ? w1 : -w1) * inv;
    }
    __syncthreads();
    float acc = 0.f;
#pragma unroll
    for (int hd = 0; hd < NHEADS; hd++) {
        const bf16* hWh = hWb + (size_t)hd * NN * HH + t;
        for (int k = 0; k < n; k++)
            acc += w_s[hd][k] * (float)hWh[(size_t)js[k] * HH];
    }
    esupb[(size_t)i * HH + t] = (bf16)(acc * (1.f / 3.f));
}

// ---------------- GRU gates (bf16 gemm outputs) ----------------
__global__ __launch_bounds__(256) void gru_gate(const bf16* __restrict__ gi, const bf16* __restrict__ gh,
                                                const float* __restrict__ bih, const float* __restrict__ bhh,
                                                const float* __restrict__ hstate, float* __restrict__ out) {
    int i = blockIdx.x;
    int t = threadIdx.x;
    size_t gbase = (size_t)i * G3;
    float ir = (float)gi[gbase + t] + bih[t];
    float iz = (float)gi[gbase + 256 + t] + bih[256 + t];
    float in_ = (float)gi[gbase + 512 + t] + bih[512 + t];
    float hr = (float)gh[gbase + t] + bhh[t];
    float hz = (float)gh[gbase + 256 + t] + bhh[256 + t];
    float hn = (float)gh[gbase + 512 + t] + bhh[512 + t];
    float r = 1.f / (1.f + __expf(-(ir + hr)));
    float z = 1.f / (1.f + __expf(-(iz + hz)));
    float nv = tanhf(in_ + r * hn);
    size_t o = (size_t)i * HH + t;
    out[o] = (1.f - z) * nv + z * hstate[o];
}

// ---------------- combine ----------------
__global__ __launch_bounds__(256) void combine_k(const float* __restrict__ de, const float* __restrict__ dn,
                                                 const float* __restrict__ eout, const float* __restrict__ nout,
                                                 float* __restrict__ out) {
    int i = blockIdx.x;
    int t = threadIdx.x;
    size_t o = (size_t)i * HH + t;
    out[o] = de[i] * eout[o] + dn[i] * nout[o];
}

extern "C" void kernel_launch(void* const* d_in, const int* in_sizes, int n_in,
                              void* d_out, int out_size, void* d_ws, size_t ws_size,
                              hipStream_t stream) {
    const float* h        = (const float*)d_in[0];
    const float* node_adj = (const float*)d_in[1];
    const float* edge_adj = (const float*)d_in[2];
    const float* gat_W    = (const float*)d_in[3];
    const float* gat_a    = (const float*)d_in[4];
    const float* e_Wih    = (const float*)d_in[5];
    const float* e_Whh    = (const float*)d_in[6];
    const float* e_bih    = (const float*)d_in[7];
    const float* e_bhh    = (const float*)d_in[8];
    const float* n_Wih    = (const float*)d_in[9];
    const float* n_Whh    = (const float*)d_in[10];
    const float* n_bih    = (const float*)d_in[11];
    const float* n_bhh    = (const float*)d_in[12];
    float* out = (float*)d_out;

    char* ws = (char*)d_ws;
    size_t off = 0;
    auto alloc = [&](size_t bytes) { char* p = ws + off; off += (bytes + 255) & ~(size_t)255; return p; };

    float* Pp    = (float*)alloc((size_t)NN * HH * 4);
    float* Pm    = (float*)alloc((size_t)NN * HH * 4);
    float* eout  = (float*)alloc((size_t)NN * HH * 4);
    float* nout  = (float*)alloc((size_t)NN * HH * 4);
    float* ep    = (float*)alloc((size_t)NHEADS * NN * 4);
    float* em    = (float*)alloc((size_t)NHEADS * NN * 4);
    float* c0    = (float*)alloc((size_t)NHEADS * HH * 4);
    float* c1    = (float*)alloc((size_t)NHEADS * HH * 4);
    float* dn    = (float*)alloc(NN * 4);
    float* de    = (float*)alloc(NN * 4);
    bf16*  hb    = (bf16*)alloc((size_t)NN * HH * 2);
    bf16*  nsupb = (bf16*)alloc((size_t)NN * HH * 2);
    bf16*  esupb = (bf16*)alloc((size_t)NN * HH * 2);
    bf16*  hWb   = (bf16*)alloc((size_t)NHEADS * NN * HH * 2);
    bf16*  gib   = (bf16*)alloc((size_t)NN * G3 * 2);
    bf16*  ghb   = (bf16*)alloc((size_t)NN * G3 * 2);
    bf16*  Weib  = (bf16*)alloc((size_t)G3 * HH * 2);
    bf16*  Wehb  = (bf16*)alloc((size_t)G3 * HH * 2);
    bf16*  Wnib  = (bf16*)alloc((size_t)G3 * HH * 2);
    bf16*  Wnhb  = (bf16*)alloc((size_t)G3 * HH * 2);
    bf16*  Wtb   = (bf16*)alloc((size_t)NHEADS * HH * HH * 2);
    int*   csr_cols = (int*)alloc((size_t)NN * MAXE * 4);
    int*   csr_nnz  = (int*)alloc(NN * 4);

    dim3 b256(256);

    // converts
    convert_bf16<<<NN * HH / 4 / 256, b256, 0, stream>>>(h, hb, NN * HH / 4);
    convert4_bf16<<<dim3(G3 * HH / 4 / 256, 4), b256, 0, stream>>>(e_Wih, e_Whh, n_Wih, n_Whh,
                                                                   Weib, Wehb, Wnib, Wnhb);
    transW_bf16<<<dim3(8, 8, 3), b256, 0, stream>>>(gat_W, Wtb);

    // adjacency scans
    node_scan<<<NN, b256, 0, stream>>>(node_adj, h, Pp, Pm, nsupb, dn);
    edge_scan<<<NN, b256, 0, stream>>>(edge_adj, csr_cols, csr_nnz, de);

    // hW = h @ W per head (batched z=3)
    gemm_bt<<<dim3(NN / 128, HH / 128, 3), b256, 0, stream>>>(
        hb, hb, hb,
        Wtb, Wtb + (size_t)HH * HH, Wtb + 2 * (size_t)HH * HH,
        hWb, hWb + (size_t)NN * HH, hWb + 2 * (size_t)NN * HH, HH);

    // GAT scalar path
    gat_c<<<NHEADS, b256, 0, stream>>>(gat_W, gat_a, c0, c1);
    gat_e<<<NN / 4, b256, 0, stream>>>(Pp, Pm, c0, c1, ep, em);
    gat_out<<<NN, b256, 0, stream>>>(csr_cols, csr_nnz, ep, em, hWb, esupb);

    // edge GRU: gi = nsup @ WihT, gh = h @ WhhT (batched z=2)
    gemm_bt<<<dim3(NN / 128, G3 / 128, 2), b256, 0, stream>>>(
        nsupb, hb, hb, Weib, Wehb, Wehb, gib, ghb, ghb, G3);
    gru_gate<<<NN, b256, 0, stream>>>(gib, ghb, e_bih, e_bhh, h, eout);

    // node GRU
    gemm_bt<<<dim3(NN / 128, G3 / 128, 2), b256, 0, stream>>>(
        esupb, hb, hb, Wnib, Wnhb, Wnhb, gib, ghb, ghb, G3);
    gru_gate<<<NN, b256, 0, stream>>>(gib, ghb, n_bih, n_bhh, h, nout);

    // out = de*edge_out + dn*node_out
    combine_k<<<NN, b256, 0, stream>>>(de, dn, eout, nout, out);
}

// Round 3
// 99.481 us; speedup vs baseline: 2.8425x; 1.3122x over previous
//
#include <hip/hip_runtime.h>
#include <hip/hip_bf16.h>
#include <math.h>

#define NN 4096
#define HH 256
#define G3 768
#define NHEADS 3
#define MAXE 128
#define ALPHA 0.2f

typedef __bf16 bf16;
typedef __attribute__((ext_vector_type(2))) __bf16 bf16x2;
typedef __attribute__((ext_vector_type(4))) __bf16 bf16x4;
typedef __attribute__((ext_vector_type(8))) __bf16 bf16x8;
typedef __attribute__((ext_vector_type(4))) float f32x4;

__device__ __forceinline__ void async_copy16(void* lds, const void* g) {
    __builtin_amdgcn_global_load_lds((const __attribute__((address_space(1))) void*)g,
                                     (__attribute__((address_space(3))) void*)lds, 16, 0, 0);
}

__device__ inline float lrelu(float x) { return x > 0.f ? x : ALPHA * x; }
__device__ inline float sigm(float x) { return 1.f / (1.f + __expf(-x)); }

// ================= prep: all converts + transposes + gat_c in one kernel =================
// blocks [0,1024): h f32->bf16
// blocks [1024,1792): 4 GRU weights f32->bf16 (192 blocks each)
// blocks [1792,1984): gat_W transpose->bf16 (3 heads x 64 tiles)
// blocks [1984,1987): gat_c (c0 = W@a_top, c1 = W@a_bot)
__global__ __launch_bounds__(256) void prep_k(
    const float* __restrict__ h,
    const float* __restrict__ eWih, const float* __restrict__ eWhh,
    const float* __restrict__ nWih, const float* __restrict__ nWhh,
    const float* __restrict__ gat_W, const float* __restrict__ gat_a,
    bf16* __restrict__ hb,
    bf16* __restrict__ Weib, bf16* __restrict__ Wehb,
    bf16* __restrict__ Wnib, bf16* __restrict__ Wnhb,
    bf16* __restrict__ Wtb, float* __restrict__ c0, float* __restrict__ c1) {
    __shared__ float tile[32][33];
    __shared__ float a_s[512];
    int b = blockIdx.x, t = threadIdx.x;
    if (b < 1024) {
        int idx = b * 256 + t;
        float4 v = *(const float4*)(h + (size_t)idx * 4);
        bf16x4 o = {(bf16)v.x, (bf16)v.y, (bf16)v.z, (bf16)v.w};
        *(bf16x4*)(hb + (size_t)idx * 4) = o;
    } else if (b < 1792) {
        int w = (b - 1024) / 192;
        int idx = ((b - 1024) % 192) * 256 + t;
        const float* in = w == 0 ? eWih : (w == 1 ? eWhh : (w == 2 ? nWih : nWhh));
        bf16* outp = w == 0 ? Weib : (w == 1 ? Wehb : (w == 2 ? Wnib : Wnhb));
        float4 v = *(const float4*)(in + (size_t)idx * 4);
        bf16x4 o = {(bf16)v.x, (bf16)v.y, (bf16)v.z, (bf16)v.w};
        *(bf16x4*)(outp + (size_t)idx * 4) = o;
    } else if (b < 1984) {
        int b2 = b - 1792;
        int hd = b2 >> 6, tl = b2 & 63;
        int k0 = (tl >> 3) * 32, n0 = (tl & 7) * 32;
        int tx = t % 32, ty = t / 32;
        const float* Wh = gat_W + (size_t)hd * HH * HH;
        for (int r = ty; r < 32; r += 8) tile[r][tx] = Wh[(size_t)(k0 + r) * HH + n0 + tx];
        __syncthreads();
        bf16* Wth = Wtb + (size_t)hd * HH * HH;
        for (int r = ty; r < 32; r += 8) Wth[(size_t)(n0 + r) * HH + k0 + tx] = (bf16)tile[tx][r];
    } else {
        int hd = b - 1984;
        a_s[t] = gat_a[(size_t)hd * 512 + t];
        a_s[t + 256] = gat_a[(size_t)hd * 512 + 256 + t];
        __syncthreads();
        const float* Wr = gat_W + (size_t)hd * HH * HH + (size_t)t * HH;
        float s0 = 0.f, s1 = 0.f;
        for (int c = 0; c < HH; c++) {
            float w = Wr[c];
            s0 += w * a_s[c];
            s1 += w * a_s[256 + c];
        }
        c0[hd * HH + t] = s0;
        c1[hd * HH + t] = s1;
    }
}

// ================= merged adjacency scan =================
// grid (NN, 2): y=0 node (gather + nsup + fused gat_e), y=1 edge (CSR + de)
__global__ __launch_bounds__(256) void scan_k(
    const float* __restrict__ node_adj, const float* __restrict__ edge_adj,
    const float* __restrict__ h,
    const float* __restrict__ c0, const float* __restrict__ c1,
    bf16* __restrict__ nsupb, float* __restrict__ dn, float* __restrict__ de,
    float* __restrict__ ep, float* __restrict__ em,
    int* __restrict__ csr_cols, int* __restrict__ csr_nnz) {
    int i = blockIdx.x, t = threadIdx.x;
    int lane = t & 63, wid = t >> 6;
    __shared__ int cnt;
    __shared__ int cols[256];
    __shared__ float part[6][4];
    if (t == 0) cnt = 0;
    __syncthreads();
    bool node = (blockIdx.y == 0);
    const float* adj = node ? node_adj : edge_adj;
    const float* row = adj + (size_t)i * NN;
    for (int base = t * 4; base < NN; base += 1024) {
        float4 v = *(const float4*)(row + base);
        float vv[4] = {v.x, v.y, v.z, v.w};
#pragma unroll
        for (int e = 0; e < 4; e++) {
            int j = base + e;
            float a = vv[e];
            if (j == i) {
                (node ? dn : de)[i] = a;
            } else if (a != 0.0f) {
                int s = atomicAdd(&cnt, 1);
                if (s < 256) cols[s] = (a > 0.0f) ? (j + 1) : -(j + 1);
            }
        }
    }
    __syncthreads();
    if (node) {
        int n = cnt < 256 ? cnt : 256;
        float accp = 0.f, accm = 0.f;
        for (int k = 0; k < n; k++) {
            int c = cols[k];
            int j = (c > 0 ? c : -c) - 1;
            float hv = h[(size_t)j * HH + t];
            if (c > 0) accp += hv; else accm += hv;
        }
        nsupb[(size_t)i * HH + t] = (bf16)(accp - accm);
        // fused gat_e: 6 block-dot-products against c0/c1
        float u[6];
#pragma unroll
        for (int hd = 0; hd < NHEADS; hd++) {
            float a0 = c0[hd * HH + t], a1 = c1[hd * HH + t];
            u[hd * 2]     = accp * a0 + accm * a1;
            u[hd * 2 + 1] = accm * a0 + accp * a1;
        }
#pragma unroll
        for (int v = 0; v < 6; v++)
#pragma unroll
            for (int off = 32; off; off >>= 1) u[v] += __shfl_xor(u[v], off);
        if (lane == 0)
#pragma unroll
            for (int v = 0; v < 6; v++) part[v][wid] = u[v];
        __syncthreads();
        if (t < 6) {
            float s = part[t][0] + part[t][1] + part[t][2] + part[t][3];
            int hd = t >> 1;
            ((t & 1) == 0 ? ep : em)[(size_t)hd * NN + i] = lrelu(s);
        }
    } else {
        int n = cnt < MAXE ? cnt : MAXE;
        if (t == 0) csr_nnz[i] = n;
        for (int k = t; k < n; k += 256) csr_cols[(size_t)i * MAXE + k] = cols[k];
    }
}

// ================= bf16 MFMA GEMM (m97 structure), z-batched up to 3 =================
// C[M,768](bf16) = A[M,256] @ Bt[768,256]^T
__global__ __launch_bounds__(256) void gemm_bt(
    const bf16* __restrict__ A0, const bf16* __restrict__ A1, const bf16* __restrict__ A2,
    const bf16* __restrict__ B0, const bf16* __restrict__ B1, const bf16* __restrict__ B2,
    bf16* __restrict__ C0, bf16* __restrict__ C1, bf16* __restrict__ C2) {
    __shared__ bf16 a_s[128 * 32];
    __shared__ bf16 b_s[128 * 32];
    int z = blockIdx.z;
    const bf16* A = z == 0 ? A0 : (z == 1 ? A1 : A2);
    const bf16* Bt = z == 0 ? B0 : (z == 1 ? B1 : B2);
    bf16* C = z == 0 ? C0 : (z == 1 ? C1 : C2);

    int tid = threadIdx.x;
    int lane = tid & 63, wid = tid >> 6;
    int wr = (wid >> 1) * 64, wc = (wid & 1) * 64;
    int i0 = blockIdx.x * 128;
    int c0n = blockIdx.y * 128;

    f32x4 acc[4][4] = {};
    int kq = (lane >> 4) * 8;

    for (int k0 = 0; k0 < 256; k0 += 32) {
        __syncthreads();
#pragma unroll
        for (int it = 0; it < 2; it++) {
            int ch = it * 256 + tid;
            int r = ch >> 2, c16 = ch & 3;
            async_copy16(&a_s[ch * 8], A + (size_t)(i0 + r) * 256 + k0 + c16 * 8);
            async_copy16(&b_s[ch * 8], Bt + (size_t)(c0n + r) * 256 + k0 + c16 * 8);
        }
        __syncthreads();
        bf16x8 af[4], bf[4];
#pragma unroll
        for (int m = 0; m < 4; m++) af[m] = *(const bf16x8*)&a_s[(wr + m * 16 + (lane & 15)) * 32 + kq];
#pragma unroll
        for (int n = 0; n < 4; n++) bf[n] = *(const bf16x8*)&b_s[(wc + n * 16 + (lane & 15)) * 32 + kq];
#pragma unroll
        for (int m = 0; m < 4; m++)
#pragma unroll
            for (int n = 0; n < 4; n++)
                acc[m][n] = __builtin_amdgcn_mfma_f32_16x16x32_bf16(af[m], bf[n], acc[m][n], 0, 0, 0);
    }
#pragma unroll
    for (int m = 0; m < 4; m++) {
#pragma unroll
        for (int n = 0; n < 4; n++) {
            int row = i0 + wr + m * 16 + (lane >> 4) * 4;
            int col = c0n + wc + n * 16 + (lane & 15);
#pragma unroll
            for (int j = 0; j < 4; j++)
                C[(size_t)(row + j) * G3 + col] = (bf16)acc[m][n][j];
        }
    }
}

// ================= GAT sparse output =================
// hWb2 layout: [NN][3*HH] (heads concatenated along columns)
__global__ __launch_bounds__(256) void gat_out(
    const int* __restrict__ csr_cols, const int* __restrict__ csr_nnz,
    const float* __restrict__ ep, const float* __restrict__ em,
    const bf16* __restrict__ hWb2, bf16* __restrict__ esupb) {
    int i = blockIdx.x, t = threadIdx.x;
    __shared__ int cols_s[MAXE];
    __shared__ int js[MAXE];
    __shared__ float w_s[NHEADS][MAXE];
    int n = csr_nnz[i];
    if (t < MAXE && t < n) {
        int c = csr_cols[(size_t)i * MAXE + t];
        cols_s[t] = c;
        js[t] = (c > 0 ? c : -c) - 1;
    }
    __syncthreads();
    int wid = t >> 6, lane = t & 63;
    if (wid < NHEADS) {
        int hd = wid;
        const float* eph = ep + (size_t)hd * NN;
        const float* emh = em + (size_t)hd * NN;
        float v0 = -1e30f, v1 = -1e30f;
        if (lane < n)      { int c = cols_s[lane];      v0 = c > 0 ? eph[js[lane]]      : emh[js[lane]]; }
        if (lane + 64 < n) { int c = cols_s[lane + 64]; v1 = c > 0 ? eph[js[lane + 64]] : emh[js[lane + 64]]; }
        float mx = fmaxf(v0, v1);
#pragma unroll
        for (int off = 32; off; off >>= 1) mx = fmaxf(mx, __shfl_xor(mx, off));
        float w0 = (lane < n) ? __expf(v0 - mx) : 0.f;
        float w1 = (lane + 64 < n) ? __expf(v1 - mx) : 0.f;
        float s = w0 + w1;
#pragma unroll
        for (int off = 32; off; off >>= 1) s += __shfl_xor(s, off);
        float inv = 1.f / s;
        if (lane < n)      w_s[hd][lane]      = (cols_s[lane] > 0 ? w0 : -w0) * inv;
        if (lane + 64 < n) w_s[hd][lane + 64] = (cols_s[lane + 64] > 0 ? w1 : -w1) * inv;
    }
    __syncthreads();
    float acc = 0.f;
#pragma unroll
    for (int hd = 0; hd < NHEADS; hd++) {
        const bf16* base = hWb2 + (size_t)hd * HH + t;
        for (int k = 0; k < n; k++)
            acc += w_s[hd][k] * (float)base[(size_t)js[k] * G3];
    }
    esupb[(size_t)i * HH + t] = (bf16)(acc * (1.f / 3.f));
}

// ================= both GRU cells + final combine, writes d_out =================
// block = 2 rows x 128 cols-pairs (each thread 2 adjacent cols)
__global__ __launch_bounds__(256) void gru_both(
    const bf16* __restrict__ gie, const bf16* __restrict__ ghe,
    const bf16* __restrict__ gin, const bf16* __restrict__ ghn,
    const float* __restrict__ ebih, const float* __restrict__ ebhh,
    const float* __restrict__ nbih, const float* __restrict__ nbhh,
    const float* __restrict__ h, const float* __restrict__ dnv, const float* __restrict__ dev,
    float* __restrict__ out) {
    int sub = threadIdx.x >> 7, tc = threadIdx.x & 127;
    int i = blockIdx.x * 2 + sub;
    int c = tc * 2;
    size_t gb = (size_t)i * G3;
    float2 hv = *(const float2*)(h + (size_t)i * HH + c);
    float De = dev[i], Dn = dnv[i];

#define LD2(p, off) (*(const bf16x2*)((p) + gb + (off) + c))
#define BI2(p, off) (*(const float2*)((p) + (off) + c))
    bf16x2 eir = LD2(gie, 0), eiz = LD2(gie, 256), ein = LD2(gie, 512);
    bf16x2 ehr = LD2(ghe, 0), ehz = LD2(ghe, 256), ehn = LD2(ghe, 512);
    bf16x2 nir = LD2(gin, 0), niz = LD2(gin, 256), nin = LD2(gin, 512);
    bf16x2 nhr = LD2(ghn, 0), nhz = LD2(ghn, 256), nhn = LD2(ghn, 512);
    float2 ebr = BI2(ebih, 0), ebz = BI2(ebih, 256), ebn = BI2(ebih, 512);
    float2 eb2r = BI2(ebhh, 0), eb2z = BI2(ebhh, 256), eb2n = BI2(ebhh, 512);
    float2 nbr = BI2(nbih, 0), nbz = BI2(nbih, 256), nbn = BI2(nbih, 512);
    float2 nb2r = BI2(nbhh, 0), nb2z = BI2(nbhh, 256), nb2n = BI2(nbhh, 512);
#undef LD2
#undef BI2

    float res[2];
#pragma unroll
    for (int j = 0; j < 2; j++) {
        float hj = j == 0 ? hv.x : hv.y;
        // edge GRU
        float r = sigm(((float)eir[j] + (j ? ebr.y : ebr.x)) + ((float)ehr[j] + (j ? eb2r.y : eb2r.x)));
        float z = sigm(((float)eiz[j] + (j ? ebz.y : ebz.x)) + ((float)ehz[j] + (j ? eb2z.y : eb2z.x)));
        float nv = tanhf(((float)ein[j] + (j ? ebn.y : ebn.x)) + r * ((float)ehn[j] + (j ? eb2n.y : eb2n.x)));
        float eo = (1.f - z) * nv + z * hj;
        // node GRU
        float r2 = sigm(((float)nir[j] + (j ? nbr.y : nbr.x)) + ((float)nhr[j] + (j ? nb2r.y : nb2r.x)));
        float z2 = sigm(((float)niz[j] + (j ? nbz.y : nbz.x)) + ((float)nhz[j] + (j ? nb2z.y : nb2z.x)));
        float nv2 = tanhf(((float)nin[j] + (j ? nbn.y : nbn.x)) + r2 * ((float)nhn[j] + (j ? nb2n.y : nb2n.x)));
        float no = (1.f - z2) * nv2 + z2 * hj;
        res[j] = De * eo + Dn * no;
    }
    *(float2*)(out + (size_t)i * HH + c) = make_float2(res[0], res[1]);
}

extern "C" void kernel_launch(void* const* d_in, const int* in_sizes, int n_in,
                              void* d_out, int out_size, void* d_ws, size_t ws_size,
                              hipStream_t stream) {
    const float* h        = (const float*)d_in[0];
    const float* node_adj = (const float*)d_in[1];
    const float* edge_adj = (const float*)d_in[2];
    const float* gat_W    = (const float*)d_in[3];
    const float* gat_a    = (const float*)d_in[4];
    const float* e_Wih    = (const float*)d_in[5];
    const float* e_Whh    = (const float*)d_in[6];
    const float* e_bih    = (const float*)d_in[7];
    const float* e_bhh    = (const float*)d_in[8];
    const float* n_Wih    = (const float*)d_in[9];
    const float* n_Whh    = (const float*)d_in[10];
    const float* n_bih    = (const float*)d_in[11];
    const float* n_bhh    = (const float*)d_in[12];
    float* out = (float*)d_out;

    char* ws = (char*)d_ws;
    size_t off = 0;
    auto alloc = [&](size_t bytes) { char* p = ws + off; off += (bytes + 255) & ~(size_t)255; return p; };

    float* ep    = (float*)alloc((size_t)NHEADS * NN * 4);
    float* em    = (float*)alloc((size_t)NHEADS * NN * 4);
    float* c0    = (float*)alloc((size_t)NHEADS * HH * 4);
    float* c1    = (float*)alloc((size_t)NHEADS * HH * 4);
    float* dn    = (float*)alloc(NN * 4);
    float* de    = (float*)alloc(NN * 4);
    bf16*  hb    = (bf16*)alloc((size_t)NN * HH * 2);
    bf16*  nsupb = (bf16*)alloc((size_t)NN * HH * 2);
    bf16*  esupb = (bf16*)alloc((size_t)NN * HH * 2);
    bf16*  hWb2  = (bf16*)alloc((size_t)NN * G3 * 2);
    bf16*  gie   = (bf16*)alloc((size_t)NN * G3 * 2);
    bf16*  ghe   = (bf16*)alloc((size_t)NN * G3 * 2);
    bf16*  gin   = (bf16*)alloc((size_t)NN * G3 * 2);
    bf16*  ghn   = (bf16*)alloc((size_t)NN * G3 * 2);
    bf16*  Weib  = (bf16*)alloc((size_t)G3 * HH * 2);
    bf16*  Wehb  = (bf16*)alloc((size_t)G3 * HH * 2);
    bf16*  Wnib  = (bf16*)alloc((size_t)G3 * HH * 2);
    bf16*  Wnhb  = (bf16*)alloc((size_t)G3 * HH * 2);
    bf16*  Wtb   = (bf16*)alloc((size_t)NHEADS * HH * HH * 2);
    int*   csr_cols = (int*)alloc((size_t)NN * MAXE * 4);
    int*   csr_nnz  = (int*)alloc(NN * 4);

    dim3 b256(256);

    // 1. prep: converts + gat_W transpose + gat_c
    prep_k<<<1987, b256, 0, stream>>>(h, e_Wih, e_Whh, n_Wih, n_Whh, gat_W, gat_a,
                                      hb, Weib, Wehb, Wnib, Wnhb, Wtb, c0, c1);

    // 2. merged scans (node: gather+nsup+gat_e fused; edge: CSR)
    scan_k<<<dim3(NN, 2), b256, 0, stream>>>(node_adj, edge_adj, h, c0, c1,
                                             nsupb, dn, de, ep, em, csr_cols, csr_nnz);

    // 3. gemmA z=3: hW (3 heads concat N=768), gi_e, gh_e
    gemm_bt<<<dim3(NN / 128, G3 / 128, 3), b256, 0, stream>>>(
        hb, nsupb, hb, Wtb, Weib, Wehb, hWb2, gie, ghe);

    // 4. GAT sparse attention output
    gat_out<<<NN, b256, 0, stream>>>(csr_cols, csr_nnz, ep, em, hWb2, esupb);

    // 5. gemmB z=2: gi_n, gh_n
    gemm_bt<<<dim3(NN / 128, G3 / 128, 2), b256, 0, stream>>>(
        esupb, hb, hb, Wnib, Wnhb, Wnhb, gin, ghn, ghn);

    // 6. both GRUs + combine -> out
    gru_both<<<NN / 2, b256, 0, stream>>>(gie, ghe, gin, ghn,
                                          e_bih, e_bhh, n_bih, n_bhh,
                                          h, dn, de, out);
}